// Round 2
// baseline (435.293 us; speedup 1.0000x reference)
//
#include <hip/hip_runtime.h>
#include <hip/hip_bf16.h>
#include <stdint.h>

#define RES 512
#define CH  32
#define NP  3
#define NTEX (NP * RES * RES)                             // 786432 texels
#define WS_BYTES ((size_t)NTEX * CH * sizeof(uint16_t))   // 48 MiB (bf16 ws)

static __device__ __forceinline__ uint16_t f2bf(float f) {
    union { float f; uint32_t u; } v; v.f = f;
    uint32_t u = v.u;
    uint32_t r = (u + 0x7fffu + ((u >> 16) & 1u)) >> 16;   // RNE
    return (uint16_t)r;
}

// ---------------------------------------------------------------------------
// Kernel 1: [3][C][R][R] fp32 -> [3][R][R][C] bf16, clipped to [-1,1].
// One thread per texel (p,y,x). Lanes consecutive in x => each channel
// iteration is a coalesced 256B wave read; write is 64B contiguous per thread.
// ---------------------------------------------------------------------------
__global__ __launch_bounds__(256) void k_transpose(const float* __restrict__ tri,
                                                   uint16_t* __restrict__ ws) {
    int t = blockIdx.x * 256 + threadIdx.x;
    if (t >= NTEX) return;
    int x = t & (RES - 1);
    int y = (t >> 9) & (RES - 1);
    int p = t >> 18;
    const float* src = tri + (size_t)p * CH * RES * RES + (size_t)y * RES + x;
    uint32_t packed[16];
#pragma unroll
    for (int i = 0; i < 16; ++i) {
        float f0 = src[(size_t)(2 * i + 0) * (RES * RES)];
        float f1 = src[(size_t)(2 * i + 1) * (RES * RES)];
        f0 = fminf(1.f, fmaxf(-1.f, f0));
        f1 = fminf(1.f, fmaxf(-1.f, f1));
        packed[i] = (uint32_t)f2bf(f0) | ((uint32_t)f2bf(f1) << 16);
    }
    uint4* dst = (uint4*)(ws + (size_t)t * CH);
#pragma unroll
    for (int i = 0; i < 4; ++i)
        dst[i] = make_uint4(packed[4 * i], packed[4 * i + 1], packed[4 * i + 2], packed[4 * i + 3]);
}

// ---------------------------------------------------------------------------
// Kernel 2: gather. One thread per point; 3 planes x 4 taps x 32ch bf16
// (4 x dwordx4 per tap), fp32 accumulate, 128B coalesced fp32 store.
// Projections (coords @ inv(PLANE_AXES[p]), first two comps):
//   p0: (x,y)=(cy,cx)   p1: (cz,cx)   p2: (cy,cz)
// ---------------------------------------------------------------------------
__global__ __launch_bounds__(256) void k_gather(const float* __restrict__ coords,
                                                const uint16_t* __restrict__ ws,
                                                float* __restrict__ out, int M) {
    int m = blockIdx.x * 256 + threadIdx.x;
    if (m >= M) return;
    float cx = coords[3 * m + 0];
    float cy = coords[3 * m + 1];
    float cz = coords[3 * m + 2];

    float acc[CH];
#pragma unroll
    for (int c = 0; c < CH; ++c) acc[c] = 0.f;

    float us[3] = {cy, cz, cy};
    float vs[3] = {cx, cx, cz};

#pragma unroll
    for (int p = 0; p < 3; ++p) {
        float px = (us[p] + 1.f) * (0.5f * (RES - 1));
        float py = (vs[p] + 1.f) * (0.5f * (RES - 1));
        float x0f = floorf(px), y0f = floorf(py);
        int x0 = (int)x0f, y0 = (int)y0f;
        float wx1 = px - x0f, wx0 = 1.f - wx1;
        float wy1 = py - y0f, wy0 = 1.f - wy1;
        int   xs[2]  = {x0, x0 + 1};
        int   ys[2]  = {y0, y0 + 1};
        float wxv[2] = {wx0, wx1};
        float wyv[2] = {wy0, wy1};
#pragma unroll
        for (int j = 0; j < 2; ++j) {
#pragma unroll
            for (int i = 0; i < 2; ++i) {
                int xi = xs[i], yi = ys[j];
                bool valid = (xi >= 0) & (xi < RES) & (yi >= 0) & (yi < RES);
                int xc = min(max(xi, 0), RES - 1);
                int yc = min(max(yi, 0), RES - 1);
                float w = valid ? (wxv[i] * wyv[j]) : 0.f;
                const uint4* tp = (const uint4*)(ws + (((size_t)p * RES + yc) * RES + xc) * CH);
#pragma unroll
                for (int q = 0; q < 4; ++q) {
                    uint4 d = tp[q];
                    uint32_t wwv[4] = {d.x, d.y, d.z, d.w};
#pragma unroll
                    for (int e = 0; e < 4; ++e) {
                        union { uint32_t u; float f; } lo, hi;
                        lo.u = wwv[e] << 16;
                        hi.u = wwv[e] & 0xffff0000u;
                        acc[q * 8 + 2 * e + 0] += w * lo.f;
                        acc[q * 8 + 2 * e + 1] += w * hi.f;
                    }
                }
            }
        }
    }

    float4* dst = (float4*)(out + (size_t)m * CH);
#pragma unroll
    for (int i = 0; i < 8; ++i)
        dst[i] = make_float4(acc[4 * i], acc[4 * i + 1], acc[4 * i + 2], acc[4 * i + 3]);
}

// ---------------------------------------------------------------------------
// Fallback (only if ws too small): gather straight from [3][C][R][R] fp32.
// Correct but strided (slow) — not expected to be used.
// ---------------------------------------------------------------------------
__global__ __launch_bounds__(256) void k_gather_direct(const float* __restrict__ coords,
                                                       const float* __restrict__ tri,
                                                       float* __restrict__ out, int M) {
    int m = blockIdx.x * 256 + threadIdx.x;
    if (m >= M) return;
    float cx = coords[3 * m + 0];
    float cy = coords[3 * m + 1];
    float cz = coords[3 * m + 2];
    float acc[CH];
#pragma unroll
    for (int c = 0; c < CH; ++c) acc[c] = 0.f;
    float us[3] = {cy, cz, cy};
    float vs[3] = {cx, cx, cz};
    for (int p = 0; p < 3; ++p) {
        float px = (us[p] + 1.f) * (0.5f * (RES - 1));
        float py = (vs[p] + 1.f) * (0.5f * (RES - 1));
        float x0f = floorf(px), y0f = floorf(py);
        int x0 = (int)x0f, y0 = (int)y0f;
        float wx1 = px - x0f, wx0 = 1.f - wx1;
        float wy1 = py - y0f, wy0 = 1.f - wy1;
        int   xs[2]  = {x0, x0 + 1};
        int   ys[2]  = {y0, y0 + 1};
        float wxv[2] = {wx0, wx1};
        float wyv[2] = {wy0, wy1};
        for (int j = 0; j < 2; ++j)
            for (int i = 0; i < 2; ++i) {
                int xi = xs[i], yi = ys[j];
                bool valid = (xi >= 0) & (xi < RES) & (yi >= 0) & (yi < RES);
                int xc = min(max(xi, 0), RES - 1);
                int yc = min(max(yi, 0), RES - 1);
                float w = valid ? (wxv[i] * wyv[j]) : 0.f;
                const float* base = tri + ((size_t)p * CH) * RES * RES + (size_t)yc * RES + xc;
#pragma unroll
                for (int c = 0; c < CH; ++c) {
                    float v = base[(size_t)c * RES * RES];
                    v = fminf(1.f, fmaxf(-1.f, v));
                    acc[c] += w * v;
                }
            }
    }
    float4* dst = (float4*)(out + (size_t)m * CH);
#pragma unroll
    for (int i = 0; i < 8; ++i)
        dst[i] = make_float4(acc[4 * i], acc[4 * i + 1], acc[4 * i + 2], acc[4 * i + 3]);
}

extern "C" void kernel_launch(void* const* d_in, const int* in_sizes, int n_in,
                              void* d_out, int out_size, void* d_ws, size_t ws_size,
                              hipStream_t stream) {
    const float* coords = (const float*)d_in[0];   // fp32 [M,3]
    const float* tri    = (const float*)d_in[1];   // fp32 [1,3,32,512,512]
    float* out          = (float*)d_out;           // fp32 [M,32]
    int M = in_sizes[0] / 3;

    if (ws_size >= WS_BYTES) {
        uint16_t* ws = (uint16_t*)d_ws;
        k_transpose<<<(NTEX + 255) / 256, 256, 0, stream>>>(tri, ws);
        k_gather<<<(M + 255) / 256, 256, 0, stream>>>(coords, ws, out, M);
    } else {
        k_gather_direct<<<(M + 255) / 256, 256, 0, stream>>>(coords, tri, out, M);
    }
}